// Round 2
// baseline (118.642 us; speedup 1.0000x reference)
//
#include <hip/hip_runtime.h>

#define DIM   512
#define RANK  64
#define TDIM  1024
#define BB    2
#define NROWS (BB * TDIM)   // 2048 flattened rows per tensor

typedef float v2f __attribute__((ext_vector_type(2)));
typedef float v4f __attribute__((ext_vector_type(4)));

__device__ __forceinline__ float fast_exp2(float x) { return __builtin_amdgcn_exp2f(x); }
__device__ __forceinline__ float fast_rcp(float x)  { return __builtin_amdgcn_rcpf(x); }

// ---------------------------------------------------------------------------
// Projection: P[row][r] = X[row][:] . W[r][:]   (full K per block, no atomics)
// grid = (NROWS/16, 2) = 256 blocks. Block: 256 threads, 16 rows x 64 r.
// Thread (ty,tx): row = ty, cols = tx+16j (j=0..3). v4f packed-fp32 dot.
// ---------------------------------------------------------------------------
__global__ __launch_bounds__(256)
void proj_kernel(const float* __restrict__ tv, const float* __restrict__ sv,
                 const float* __restrict__ Wt, const float* __restrict__ Ws,
                 float* __restrict__ pt, float* __restrict__ ps)
{
    const int which = blockIdx.y;
    const float* X = which ? sv : tv;
    const float* W = which ? Ws : Wt;
    float* P       = which ? ps : pt;

    const int row0 = blockIdx.x * 16;
    const int tid  = threadIdx.x;
    const int tx   = tid & 15;
    const int ty   = tid >> 4;

    __shared__ float xs[16][68];
    __shared__ float wsm[64][68];

    v4f acc[4];
#pragma unroll
    for (int j = 0; j < 4; j++) acc[j] = (v4f)0.f;

    for (int kc = 0; kc < DIM; kc += 64) {
        // stage X chunk (16x64) and W chunk (64x64), coalesced float4
        {
            const int r = tid >> 4;
            const int c = (tid & 15) * 4;
            *(v4f*)&xs[r][c] = *(const v4f*)&X[(size_t)(row0 + r) * DIM + kc + c];
#pragma unroll
            for (int p = 0; p < 4; p++) {
                const int wr = (tid >> 4) + p * 16;
                *(v4f*)&wsm[wr][c] = *(const v4f*)&W[(size_t)wr * DIM + kc + c];
            }
        }
        __syncthreads();

#pragma unroll 4
        for (int k4 = 0; k4 < 64; k4 += 4) {
            const v4f av = *(const v4f*)&xs[ty][k4];       // broadcast across tx
#pragma unroll
            for (int j = 0; j < 4; j++) {
                const v4f bv = *(const v4f*)&wsm[tx + 16 * j][k4];
                acc[j] += av * bv;                          // v_pk_fma_f32 x2
            }
        }
        __syncthreads();
    }

#pragma unroll
    for (int j = 0; j < 4; j++) {
        const float s = (acc[j].x + acc[j].y) + (acc[j].z + acc[j].w);
        P[(size_t)(row0 + ty) * RANK + tx + 16 * j] = s;
    }
}

// ---------------------------------------------------------------------------
// Pairwise: out[b][t][s] = sum_r iw[r]*silu(pt[b,t,r]*ps[b,s,r])
//                          + tl[b,t] + sl[b,s] + bias
// grid = (16,16,2) = 512 blocks, 2 blocks/CU, 8 waves/CU.
// Inner loop packed over k-pairs: v_pk_mul/add/fma; exp2/rcp scalar (1/4 rate,
// the floor: 16 of ~20 cyc/element).
// ---------------------------------------------------------------------------
__global__ __launch_bounds__(256)
void pair_kernel(const float* __restrict__ pt, const float* __restrict__ ps,
                 const float* __restrict__ wt_out, const float* __restrict__ ws_out,
                 const float* __restrict__ iw, const float* __restrict__ bias_p,
                 float* __restrict__ out)
{
    const int b  = blockIdx.z;
    const int t0 = blockIdx.y * 64;
    const int s0 = blockIdx.x * 64;
    const int tid = threadIdx.x;
    const int tx  = tid & 15;
    const int ty  = tid >> 4;

    __shared__ float pts[64][68];
    __shared__ float sts[64][68];
    __shared__ __align__(16) float wsh[64];
    __shared__ float tlsh[64];
    __shared__ float slsh[64];

    const float* ptb = pt + ((size_t)b * TDIM + t0) * RANK;
    const float* psb = ps + ((size_t)b * TDIM + s0) * RANK;

#pragma unroll
    for (int p = 0; p < 4; p++) {
        const int r = (tid >> 4) + p * 16;
        const int c = (tid & 15) * 4;
        *(v4f*)&pts[r][c] = *(const v4f*)&ptb[(size_t)r * RANK + c];
        *(v4f*)&sts[r][c] = *(const v4f*)&psb[(size_t)r * RANK + c];
    }
    if (tid < 64) wsh[tid] = iw[tid];
    __syncthreads();

    // per-block target/source linear terms (one wave each)
    if (tid < 64) {
        float v = 0.f;
#pragma unroll 8
        for (int r = 0; r < RANK; r++) v = fmaf(pts[tid][r], wt_out[r], v);
        tlsh[tid] = v;
    } else if (tid < 128) {
        const int s = tid - 64;
        float v = 0.f;
#pragma unroll 8
        for (int r = 0; r < RANK; r++) v = fmaf(sts[s][r], ws_out[r], v);
        slsh[s] = v;
    }
    __syncthreads();

    const float bias = bias_p[0];
    const float NL2E = -1.44269504088896340736f;  // -log2(e)

    v2f acc[4][4];
#pragma unroll
    for (int i = 0; i < 4; i++)
#pragma unroll
        for (int j = 0; j < 4; j++) acc[i][j] = (v2f)0.f;

    for (int r4 = 0; r4 < RANK; r4 += 4) {
        const v4f wv = *(const v4f*)&wsh[r4];

        v4f a2[4], wa[4], bv[4];
#pragma unroll
        for (int i = 0; i < 4; i++) {
            const v4f av = *(const v4f*)&pts[ty + 16 * i][r4];  // broadcast in tx
            a2[i] = av * NL2E;    // feeds exp2
            wa[i] = av * wv;      // w*a, feeds w*z
        }
#pragma unroll
        for (int j = 0; j < 4; j++)
            bv[j] = *(const v4f*)&sts[tx + 16 * j][r4];         // 2-way bank = free

#pragma unroll
        for (int i = 0; i < 4; i++)
#pragma unroll
            for (int j = 0; j < 4; j++) {
                // z = a*b ; contribution = (w*z) * sigmoid(z)
                const v2f t0v = a2[i].lo * bv[j].lo;   // -z*log2e, k pair 0
                const v2f t1v = a2[i].hi * bv[j].hi;   // k pair 1
                v2f e0, e1;
                e0.x = fast_exp2(t0v.x); e0.y = fast_exp2(t0v.y);
                e1.x = fast_exp2(t1v.x); e1.y = fast_exp2(t1v.y);
                const v2f d0 = e0 + 1.0f;
                const v2f d1 = e1 + 1.0f;
                v2f r0, r1;
                r0.x = fast_rcp(d0.x); r0.y = fast_rcp(d0.y);
                r1.x = fast_rcp(d1.x); r1.y = fast_rcp(d1.y);
                const v2f w0 = wa[i].lo * bv[j].lo;    // w*z, k pair 0
                const v2f w1 = wa[i].hi * bv[j].hi;
                acc[i][j] += w0 * r0;                   // v_pk_fma_f32
                acc[i][j] += w1 * r1;
            }
    }

    // epilogue: add linears + bias, coalesced scalar stores (lane tx contiguous)
#pragma unroll
    for (int i = 0; i < 4; i++) {
        const int t = t0 + ty + 16 * i;
        const float tl = tlsh[ty + 16 * i];
        float* orow = out + ((size_t)b * TDIM + t) * TDIM + s0;
#pragma unroll
        for (int j = 0; j < 4; j++) {
            const float v = acc[i][j].x + acc[i][j].y;
            orow[tx + 16 * j] = v + tl + slsh[tx + 16 * j] + bias;
        }
    }
}

// ---------------------------------------------------------------------------
extern "C" void kernel_launch(void* const* d_in, const int* in_sizes, int n_in,
                              void* d_out, int out_size, void* d_ws, size_t ws_size,
                              hipStream_t stream)
{
    const float* tv     = (const float*)d_in[0];  // [2,1024,512]
    const float* sv     = (const float*)d_in[1];  // [2,1024,512]
    const float* Wt     = (const float*)d_in[2];  // [64,512]
    const float* Ws     = (const float*)d_in[3];  // [64,512]
    const float* wt_out = (const float*)d_in[4];  // [64]
    const float* ws_out = (const float*)d_in[5];  // [64]
    const float* iw     = (const float*)d_in[6];  // [64]
    const float* bias   = (const float*)d_in[7];  // scalar
    float* out = (float*)d_out;                   // [2,1024,1024]

    float* pt = (float*)d_ws;                          // [2048][64]
    float* ps = pt + (size_t)NROWS * RANK;             // [2048][64]

    dim3 pgrid(NROWS / 16, 2);
    proj_kernel<<<pgrid, 256, 0, stream>>>(tv, sv, Wt, Ws, pt, ps);

    dim3 ggrid(TDIM / 64, TDIM / 64, BB);
    pair_kernel<<<ggrid, 256, 0, stream>>>(pt, ps, wt_out, ws_out, iw, bias, out);
}

// Round 3
// 117.097 us; speedup vs baseline: 1.0132x; 1.0132x over previous
//
#include <hip/hip_runtime.h>

#define DIM   512
#define RANK  64
#define TDIM  1024
#define BB    2
#define NROWS (BB * TDIM)   // 2048 flattened rows per tensor

typedef float v4f __attribute__((ext_vector_type(4)));

__device__ __forceinline__ float fast_exp2(float x) { return __builtin_amdgcn_exp2f(x); }
__device__ __forceinline__ float fast_rcp(float x)  { return __builtin_amdgcn_rcpf(x); }

// ---------------------------------------------------------------------------
// Projection: P[row][r] = X[row][:] . W[r][:]   (full K per block, no atomics)
// grid = (NROWS/16, 2) = 256 blocks (1/CU). Block: 256 threads, 16 rows x 64 r.
// ---------------------------------------------------------------------------
__global__ __launch_bounds__(256)
void proj_kernel(const float* __restrict__ tv, const float* __restrict__ sv,
                 const float* __restrict__ Wt, const float* __restrict__ Ws,
                 float* __restrict__ pt, float* __restrict__ ps)
{
    const int which = blockIdx.y;
    const float* X = which ? sv : tv;
    const float* W = which ? Ws : Wt;
    float* P       = which ? ps : pt;

    const int row0 = blockIdx.x * 16;
    const int tid  = threadIdx.x;
    const int tx   = tid & 15;
    const int ty   = tid >> 4;

    __shared__ float xs[16][68];
    __shared__ float wsm[64][68];

    float acc[4][4];
#pragma unroll
    for (int j = 0; j < 4; j++)
#pragma unroll
        for (int k = 0; k < 4; k++) acc[j][k] = 0.f;

    for (int kc = 0; kc < DIM; kc += 64) {
        {
            const int r = tid >> 4;
            const int c = (tid & 15) * 4;
            *(v4f*)&xs[r][c] = *(const v4f*)&X[(size_t)(row0 + r) * DIM + kc + c];
#pragma unroll
            for (int p = 0; p < 4; p++) {
                const int wr = (tid >> 4) + p * 16;
                *(v4f*)&wsm[wr][c] = *(const v4f*)&W[(size_t)wr * DIM + kc + c];
            }
        }
        __syncthreads();

#pragma unroll 4
        for (int k4 = 0; k4 < 64; k4 += 4) {
            const v4f av = *(const v4f*)&xs[ty][k4];       // broadcast across tx
            const float a0 = av.x, a1 = av.y, a2 = av.z, a3 = av.w;
#pragma unroll
            for (int j = 0; j < 4; j++) {
                const v4f bv = *(const v4f*)&wsm[tx + 16 * j][k4];
                acc[j][0] = fmaf(a0, bv.x, acc[j][0]);
                acc[j][1] = fmaf(a1, bv.y, acc[j][1]);
                acc[j][2] = fmaf(a2, bv.z, acc[j][2]);
                acc[j][3] = fmaf(a3, bv.w, acc[j][3]);
            }
        }
        __syncthreads();
    }

#pragma unroll
    for (int j = 0; j < 4; j++) {
        const float s = (acc[j][0] + acc[j][1]) + (acc[j][2] + acc[j][3]);
        P[(size_t)(row0 + ty) * RANK + tx + 16 * j] = s;
    }
}

// ---------------------------------------------------------------------------
// Pairwise: out[b][t][s] = sum_r iw[r]*silu(pt[b,t,r]*ps[b,s,r])
//                          + tl[b,t] + sl[b,s] + bias
// grid = (16,16,2) = 512 blocks, 2 blocks/CU.
// Inner loop is the minimal 6-inst scalar sequence per element:
//   t = a2*b; e = exp2(t); d = e+1; r = rcp(d); wz = wa*b; acc = fma(wz,r,acc)
// 4 full-rate (8 cyc) + 2 transcendental (16 cyc) = 24 cyc/wave-element
// -> ALU floor ~20.5 us over 2.097M wave-elements on 1024 SIMDs.
// ---------------------------------------------------------------------------
__global__ __launch_bounds__(256)
void pair_kernel(const float* __restrict__ pt, const float* __restrict__ ps,
                 const float* __restrict__ wt_out, const float* __restrict__ ws_out,
                 const float* __restrict__ iw, const float* __restrict__ bias_p,
                 float* __restrict__ out)
{
    const int b  = blockIdx.z;
    const int t0 = blockIdx.y * 64;
    const int s0 = blockIdx.x * 64;
    const int tid = threadIdx.x;
    const int tx  = tid & 15;
    const int ty  = tid >> 4;

    __shared__ float pts[64][68];
    __shared__ float sts[64][68];
    __shared__ __align__(16) float wsh[64];
    __shared__ float tlsh[64];
    __shared__ float slsh[64];

    const float* ptb = pt + ((size_t)b * TDIM + t0) * RANK;
    const float* psb = ps + ((size_t)b * TDIM + s0) * RANK;

#pragma unroll
    for (int p = 0; p < 4; p++) {
        const int r = (tid >> 4) + p * 16;
        const int c = (tid & 15) * 4;
        *(v4f*)&pts[r][c] = *(const v4f*)&ptb[(size_t)r * RANK + c];
        *(v4f*)&sts[r][c] = *(const v4f*)&psb[(size_t)r * RANK + c];
    }
    if (tid < 64) wsh[tid] = iw[tid];
    __syncthreads();

    // per-block target/source linear terms (one wave each)
    if (tid < 64) {
        float v = 0.f;
#pragma unroll 8
        for (int r = 0; r < RANK; r++) v = fmaf(pts[tid][r], wt_out[r], v);
        tlsh[tid] = v;
    } else if (tid < 128) {
        const int s = tid - 64;
        float v = 0.f;
#pragma unroll 8
        for (int r = 0; r < RANK; r++) v = fmaf(sts[s][r], ws_out[r], v);
        slsh[s] = v;
    }
    __syncthreads();

    const float bias = bias_p[0];
    const float NL2E = -1.44269504088896340736f;  // -log2(e)

    float acc[4][4];
#pragma unroll
    for (int i = 0; i < 4; i++)
#pragma unroll
        for (int j = 0; j < 4; j++) acc[i][j] = 0.f;

    for (int r4 = 0; r4 < RANK; r4 += 4) {
        const v4f wv4 = *(const v4f*)&wsh[r4];
        const float wv[4] = {wv4.x, wv4.y, wv4.z, wv4.w};

        float a2[4][4], wa[4][4], bv[4][4];
#pragma unroll
        for (int i = 0; i < 4; i++) {
            const v4f av = *(const v4f*)&pts[ty + 16 * i][r4];  // 4 rows, 4 banks: free
            const float avv[4] = {av.x, av.y, av.z, av.w};
#pragma unroll
            for (int k = 0; k < 4; k++) {
                a2[i][k] = avv[k] * NL2E;   // feeds exp2
                wa[i][k] = avv[k] * wv[k];  // feeds w*z
            }
        }
#pragma unroll
        for (int j = 0; j < 4; j++) {
            const v4f bb = *(const v4f*)&sts[tx + 16 * j][r4];  // 2-way bank: free
            bv[j][0] = bb.x; bv[j][1] = bb.y; bv[j][2] = bb.z; bv[j][3] = bb.w;
        }

#pragma unroll
        for (int i = 0; i < 4; i++)
#pragma unroll
            for (int j = 0; j < 4; j++)
#pragma unroll
                for (int k = 0; k < 4; k++) {
                    const float t  = a2[i][k] * bv[j][k];   // -z*log2e
                    const float e  = fast_exp2(t);          // exp(-z)
                    const float d  = e + 1.0f;
                    const float r  = fast_rcp(d);           // sigmoid(z)
                    const float wz = wa[i][k] * bv[j][k];   // w*z
                    acc[i][j] = fmaf(wz, r, acc[i][j]);
                }
    }

    // epilogue: add linears + bias, coalesced scalar stores
#pragma unroll
    for (int i = 0; i < 4; i++) {
        const int t = t0 + ty + 16 * i;
        const float tl = tlsh[ty + 16 * i];
        float* orow = out + ((size_t)b * TDIM + t) * TDIM + s0;
#pragma unroll
        for (int j = 0; j < 4; j++) {
            orow[tx + 16 * j] = acc[i][j] + tl + slsh[tx + 16 * j] + bias;
        }
    }
}

// ---------------------------------------------------------------------------
extern "C" void kernel_launch(void* const* d_in, const int* in_sizes, int n_in,
                              void* d_out, int out_size, void* d_ws, size_t ws_size,
                              hipStream_t stream)
{
    const float* tv     = (const float*)d_in[0];  // [2,1024,512]
    const float* sv     = (const float*)d_in[1];  // [2,1024,512]
    const float* Wt     = (const float*)d_in[2];  // [64,512]
    const float* Ws     = (const float*)d_in[3];  // [64,512]
    const float* wt_out = (const float*)d_in[4];  // [64]
    const float* ws_out = (const float*)d_in[5];  // [64]
    const float* iw     = (const float*)d_in[6];  // [64]
    const float* bias   = (const float*)d_in[7];  // scalar
    float* out = (float*)d_out;                   // [2,1024,1024]

    float* pt = (float*)d_ws;                          // [2048][64]
    float* ps = pt + (size_t)NROWS * RANK;             // [2048][64]

    dim3 pgrid(NROWS / 16, 2);
    proj_kernel<<<pgrid, 256, 0, stream>>>(tv, sv, Wt, Ws, pt, ps);

    dim3 ggrid(TDIM / 64, TDIM / 64, BB);
    pair_kernel<<<ggrid, 256, 0, stream>>>(pt, ps, wt_out, ws_out, iw, bias, out);
}

// Round 4
// 114.734 us; speedup vs baseline: 1.0341x; 1.0206x over previous
//
#include <hip/hip_runtime.h>

#define DIM   512
#define RANK  64
#define TDIM  1024
#define BB    2
#define NROWS (BB * TDIM)   // 2048 flattened rows per tensor

typedef float v4f __attribute__((ext_vector_type(4)));

__device__ __forceinline__ float fast_exp2(float x) { return __builtin_amdgcn_exp2f(x); }
__device__ __forceinline__ float fast_rcp(float x)  { return __builtin_amdgcn_rcpf(x); }

// ---------------------------------------------------------------------------
// Projection: P[row][r] += X[row][kc:kc+64] . W[r][kc:kc+64]
// grid = (NROWS/64, DIM/64, 2) = 512 blocks (2/CU). 64x64 tile, 4x4 micro.
// 8 ds_read_b128 per 64 FMA (vs 5 per 16 in the old 16-row layout).
// Split-K accumulated via atomicAdd into memset-zeroed workspace.
// ---------------------------------------------------------------------------
__global__ __launch_bounds__(256)
void proj_kernel(const float* __restrict__ tv, const float* __restrict__ sv,
                 const float* __restrict__ Wt, const float* __restrict__ Ws,
                 float* __restrict__ pt, float* __restrict__ ps)
{
    const int which = blockIdx.z;
    const float* X = which ? sv : tv;
    const float* W = which ? Ws : Wt;
    float* P       = which ? ps : pt;

    const int row0 = blockIdx.x * 64;
    const int kc   = blockIdx.y * 64;
    const int tid  = threadIdx.x;
    const int tx   = tid & 15;
    const int ty   = tid >> 4;

    __shared__ float xs[64][68];
    __shared__ float wsm[64][68];

#pragma unroll
    for (int p = 0; p < 4; p++) {
        const int r = (tid >> 4) + p * 16;
        const int c = (tid & 15) * 4;
        *(v4f*)&xs[r][c]  = *(const v4f*)&X[(size_t)(row0 + r) * DIM + kc + c];
        *(v4f*)&wsm[r][c] = *(const v4f*)&W[(size_t)r * DIM + kc + c];
    }
    __syncthreads();

    float acc[4][4];
#pragma unroll
    for (int i = 0; i < 4; i++)
#pragma unroll
        for (int j = 0; j < 4; j++) acc[i][j] = 0.f;

#pragma unroll 2
    for (int k4 = 0; k4 < 64; k4 += 4) {
        v4f a[4], b[4];
#pragma unroll
        for (int i = 0; i < 4; i++) a[i] = *(const v4f*)&xs[ty + 16 * i][k4];   // broadcast
#pragma unroll
        for (int j = 0; j < 4; j++) b[j] = *(const v4f*)&wsm[tx + 16 * j][k4];  // 2-way: free
#pragma unroll
        for (int i = 0; i < 4; i++)
#pragma unroll
            for (int j = 0; j < 4; j++) {
                acc[i][j] = fmaf(a[i].x, b[j].x, acc[i][j]);
                acc[i][j] = fmaf(a[i].y, b[j].y, acc[i][j]);
                acc[i][j] = fmaf(a[i].z, b[j].z, acc[i][j]);
                acc[i][j] = fmaf(a[i].w, b[j].w, acc[i][j]);
            }
    }

#pragma unroll
    for (int i = 0; i < 4; i++)
#pragma unroll
        for (int j = 0; j < 4; j++)
            atomicAdd(&P[(size_t)(row0 + ty + 16 * i) * RANK + tx + 16 * j], acc[i][j]);
}

// ---------------------------------------------------------------------------
// Pairwise: out[b][t][s] = sum_r iw[r]*silu(pt[b,t,r]*ps[b,s,r])
//                          + tl[b,t] + sl[b,s] + bias
// grid = (16, 32, 2) = 1024 blocks (4/CU, 16 waves/CU). Tile 32(t) x 64(s),
// micro 2x4 per thread.
// Paired-reciprocal: for elements (k, k+1) share one rcp:
//   r = rcp(d0*d1); sig0 = r*d1; sig1 = r*d0   (exact algebra)
// Per element: trans pipe 12 cyc (1 exp + 0.5 rcp), VALU 11 cyc.
// ---------------------------------------------------------------------------
__global__ __launch_bounds__(256)
void pair_kernel(const float* __restrict__ pt, const float* __restrict__ ps,
                 const float* __restrict__ wt_out, const float* __restrict__ ws_out,
                 const float* __restrict__ iw, const float* __restrict__ bias_p,
                 float* __restrict__ out)
{
    const int b  = blockIdx.z;
    const int t0 = blockIdx.y * 32;
    const int s0 = blockIdx.x * 64;
    const int tid = threadIdx.x;
    const int tx  = tid & 15;
    const int ty  = tid >> 4;

    __shared__ float pts[32][68];
    __shared__ float sts[64][68];
    __shared__ __align__(16) float wsh[64];
    __shared__ float tlsh[32];
    __shared__ float slsh[64];

    const float* ptb = pt + ((size_t)b * TDIM + t0) * RANK;
    const float* psb = ps + ((size_t)b * TDIM + s0) * RANK;

#pragma unroll
    for (int p = 0; p < 2; p++) {
        const int r = (tid >> 4) + p * 16;
        const int c = (tid & 15) * 4;
        *(v4f*)&pts[r][c] = *(const v4f*)&ptb[(size_t)r * RANK + c];
    }
#pragma unroll
    for (int p = 0; p < 4; p++) {
        const int r = (tid >> 4) + p * 16;
        const int c = (tid & 15) * 4;
        *(v4f*)&sts[r][c] = *(const v4f*)&psb[(size_t)r * RANK + c];
    }
    if (tid < 64) wsh[tid] = iw[tid];
    __syncthreads();

    // per-block linear terms
    if (tid < 32) {
        float v = 0.f;
#pragma unroll 8
        for (int r = 0; r < RANK; r++) v = fmaf(pts[tid][r], wt_out[r], v);
        tlsh[tid] = v;
    } else if (tid >= 64 && tid < 128) {
        const int s = tid - 64;
        float v = 0.f;
#pragma unroll 8
        for (int r = 0; r < RANK; r++) v = fmaf(sts[s][r], ws_out[r], v);
        slsh[s] = v;
    }
    __syncthreads();

    const float bias = bias_p[0];
    const float NL2E = -1.44269504088896340736f;  // -log2(e)

    float acc[2][4];
#pragma unroll
    for (int i = 0; i < 2; i++)
#pragma unroll
        for (int j = 0; j < 4; j++) acc[i][j] = 0.f;

    for (int r4 = 0; r4 < RANK; r4 += 4) {
        const v4f wv4 = *(const v4f*)&wsh[r4];
        const float wv[4] = {wv4.x, wv4.y, wv4.z, wv4.w};

        float a2[2][4], wa[2][4], bv[4][4];
#pragma unroll
        for (int i = 0; i < 2; i++) {
            const v4f av = *(const v4f*)&pts[ty + 16 * i][r4];   // broadcast per 16-group
            const float avv[4] = {av.x, av.y, av.z, av.w};
#pragma unroll
            for (int k = 0; k < 4; k++) {
                a2[i][k] = avv[k] * NL2E;   // feeds exp2
                wa[i][k] = avv[k] * wv[k];  // feeds w*z
            }
        }
#pragma unroll
        for (int j = 0; j < 4; j++) {
            const v4f bb = *(const v4f*)&sts[tx + 16 * j][r4];   // 2-way bank: free
            bv[j][0] = bb.x; bv[j][1] = bb.y; bv[j][2] = bb.z; bv[j][3] = bb.w;
        }

#pragma unroll
        for (int i = 0; i < 2; i++)
#pragma unroll
            for (int j = 0; j < 4; j++)
#pragma unroll
                for (int k2 = 0; k2 < 4; k2 += 2) {
                    const float t0v = a2[i][k2]     * bv[j][k2];
                    const float t1v = a2[i][k2 + 1] * bv[j][k2 + 1];
                    const float e0  = fast_exp2(t0v);            // exp(-z0)
                    const float e1  = fast_exp2(t1v);            // exp(-z1)
                    const float d0  = e0 + 1.0f;
                    const float d1  = e1 + 1.0f;
                    const float r   = fast_rcp(d0 * d1);         // shared reciprocal
                    const float s0  = r * d1;                    // sigmoid(z0)
                    const float s1  = r * d0;                    // sigmoid(z1)
                    const float wz0 = wa[i][k2]     * bv[j][k2];
                    const float wz1 = wa[i][k2 + 1] * bv[j][k2 + 1];
                    acc[i][j] = fmaf(wz0, s0, acc[i][j]);
                    acc[i][j] = fmaf(wz1, s1, acc[i][j]);
                }
    }

    // epilogue
#pragma unroll
    for (int i = 0; i < 2; i++) {
        const int t = t0 + ty + 16 * i;
        const float tl = tlsh[ty + 16 * i];
        float* orow = out + ((size_t)b * TDIM + t) * TDIM + s0;
#pragma unroll
        for (int j = 0; j < 4; j++) {
            orow[tx + 16 * j] = acc[i][j] + tl + slsh[tx + 16 * j] + bias;
        }
    }
}

// ---------------------------------------------------------------------------
extern "C" void kernel_launch(void* const* d_in, const int* in_sizes, int n_in,
                              void* d_out, int out_size, void* d_ws, size_t ws_size,
                              hipStream_t stream)
{
    const float* tv     = (const float*)d_in[0];  // [2,1024,512]
    const float* sv     = (const float*)d_in[1];  // [2,1024,512]
    const float* Wt     = (const float*)d_in[2];  // [64,512]
    const float* Ws     = (const float*)d_in[3];  // [64,512]
    const float* wt_out = (const float*)d_in[4];  // [64]
    const float* ws_out = (const float*)d_in[5];  // [64]
    const float* iw     = (const float*)d_in[6];  // [64]
    const float* bias   = (const float*)d_in[7];  // scalar
    float* out = (float*)d_out;                   // [2,1024,1024]

    float* pt = (float*)d_ws;                          // [2048][64]
    float* ps = pt + (size_t)NROWS * RANK;             // [2048][64]

    // zero projection accumulators (split-K atomics)
    hipMemsetAsync(d_ws, 0, 2 * (size_t)NROWS * RANK * sizeof(float), stream);

    dim3 pgrid(NROWS / 64, DIM / 64, 2);
    proj_kernel<<<pgrid, 256, 0, stream>>>(tv, sv, Wt, Ws, pt, ps);

    dim3 ggrid(TDIM / 64, TDIM / 32, BB);
    pair_kernel<<<ggrid, 256, 0, stream>>>(pt, ps, wt_out, ws_out, iw, bias, out);
}